// Round 1
// 1713.888 us; speedup vs baseline: 1.1243x; 1.1243x over previous
//
#include <hip/hip_runtime.h>
#include <hip/hip_bf16.h>
#include <stdint.h>

// Problem constants (fixed by the reference)
#define TOKENS 8192
#define IN_F   4096
#define OUT_F  16384

typedef __bf16 bf16;
typedef __bf16 bf16x8 __attribute__((ext_vector_type(8)));
typedef float  f32x4  __attribute__((ext_vector_type(4)));

__device__ __constant__ float NF4[16] = {
    -1.0f, -0.6961928009986877f, -0.5250730514526367f, -0.39491748809814453f,
    -0.28444138169288635f, -0.18477343022823334f, -0.09105003625154495f, 0.0f,
    0.07958029955625534f, 0.16093020141124725f, 0.24611230194568634f,
    0.33791524171829224f, 0.44070982933044434f, 0.5626170039176941f,
    0.7229568362236023f, 1.0f};

// ---------- x fp32 -> bf16 ----------
__global__ __launch_bounds__(256) void cvt_kernel(const float* __restrict__ x,
                                                  bf16* __restrict__ xb) {
    size_t base = ((size_t)blockIdx.x * blockDim.x + threadIdx.x) * 8;
    float4 a = *(const float4*)(x + base);
    float4 b = *(const float4*)(x + base + 4);
    bf16x8 w;
    w[0] = (bf16)a.x; w[1] = (bf16)a.y; w[2] = (bf16)a.z; w[3] = (bf16)a.w;
    w[4] = (bf16)b.x; w[5] = (bf16)b.y; w[6] = (bf16)b.z; w[7] = (bf16)b.w;
    *(bf16x8*)(xb + base) = w;
}

// ---------- NF4 dequant: codes(int32)+absmax -> W bf16 [OUT_F][IN_F] ----------
__global__ __launch_bounds__(256) void dequant_kernel(const int* __restrict__ codes,
                                                      const float* __restrict__ absmax,
                                                      bf16* __restrict__ W) {
    __shared__ float lut[16];
    if (threadIdx.x < 16) lut[threadIdx.x] = NF4[threadIdx.x];
    __syncthreads();
    size_t base = ((size_t)blockIdx.x * blockDim.x + threadIdx.x) * 8;
    float scale = absmax[base >> 6];   // 8 consecutive elems share one 64-block
    int4 c0 = *(const int4*)(codes + base);
    int4 c1 = *(const int4*)(codes + base + 4);
    bf16x8 w;
    w[0] = (bf16)(lut[c0.x] * scale);
    w[1] = (bf16)(lut[c0.y] * scale);
    w[2] = (bf16)(lut[c0.z] * scale);
    w[3] = (bf16)(lut[c0.w] * scale);
    w[4] = (bf16)(lut[c1.x] * scale);
    w[5] = (bf16)(lut[c1.y] * scale);
    w[6] = (bf16)(lut[c1.z] * scale);
    w[7] = (bf16)(lut[c1.w] * scale);
    *(bf16x8*)(W + base) = w;
}

typedef const unsigned int __attribute__((address_space(1)))* gas_ptr;
typedef unsigned int __attribute__((address_space(3)))* las_ptr;

__device__ __forceinline__ void async_load16(const void* g, void* l) {
    __builtin_amdgcn_global_load_lds((gas_ptr)(uintptr_t)g, (las_ptr)(uintptr_t)l, 16, 0, 0);
}

// ======================================================================
// 256x256 tile, BK=64, 8 waves (2M x 4N), double-buffered 128KB LDS.
// T2: XOR swizzle f ^= ((f>>7)&7)<<4 applied via pre-swizzled global source
//     (LDS written linearly by global_load_lds) + swizzled ds_read addrs.
// T3/T4: phase-split K-step with counted s_waitcnt vmcnt(8) — never drains
//     to 0 in the main loop; tile t+2's loads ride across tile t+1's compute.
// T5: s_setprio(1) around each 16-MFMA cluster.
// Raw s_barrier (no vmcnt drain) fenced by sched_barrier(0).
// ======================================================================
#define GBM 256
#define GBN 256
#define GBK 64
#define GNT (IN_F / GBK)   // 64 K-tiles

__device__ __forceinline__ void bar_nodrain() {
    __builtin_amdgcn_sched_barrier(0);
    __builtin_amdgcn_s_barrier();
    __builtin_amdgcn_sched_barrier(0);
}

#define CLUSTER(I0, J0)                                                          \
    do {                                                                         \
        __builtin_amdgcn_s_setprio(1);                                           \
        _Pragma("unroll") for (int i_ = 0; i_ < 4; ++i_) {                       \
            _Pragma("unroll") for (int j_ = 0; j_ < 2; ++j_) {                   \
                acc[(I0) + i_][(J0) + j_] = __builtin_amdgcn_mfma_f32_16x16x32_bf16( \
                    a[i_][0], b[(J0) + j_][0], acc[(I0) + i_][(J0) + j_], 0, 0, 0);  \
                acc[(I0) + i_][(J0) + j_] = __builtin_amdgcn_mfma_f32_16x16x32_bf16( \
                    a[i_][1], b[(J0) + j_][1], acc[(I0) + i_][(J0) + j_], 0, 0, 0);  \
            }                                                                    \
        }                                                                        \
        __builtin_amdgcn_s_setprio(0);                                           \
    } while (0)

__global__ __launch_bounds__(512, 2) void gemm256(const bf16* __restrict__ A,   // [M][K]
                                                  const bf16* __restrict__ B,   // [N][K]
                                                  const float* __restrict__ bias,
                                                  float* __restrict__ C) {      // [M][N]
    constexpr int K = IN_F, N = OUT_F;
    extern __shared__ char smem[];  // 131072: buf0{A 32K, B 32K} buf1{A 32K, B 32K}

    const int t    = threadIdx.x;
    const int wave = t >> 6, lane = t & 63;
    const int quad = lane >> 4, r16 = lane & 15;
    const int wr = wave >> 2, wc = wave & 3;   // 2 (M) x 4 (N) waves

    // XCD-aware bijective swizzle: 2048 blocks, 8 XCDs, 256 per chunk
    const int g  = blockIdx.x;
    const int s  = (g & 7) * (2048 / 8) + (g >> 3);
    const int by = s >> 6;          // 32 M-tiles
    const int bx = s & 63;          // 64 N-tiles
    const int m0 = by * GBM;
    const int n0 = bx * GBN;

    // --- staging source mapping (involution: logical f = phys w ^ ((w>>7&7)<<4)) ---
    // global_load_lds writes linearly (wave base + lane*16); pre-swizzle the SOURCE.
    const int wl    = wave * 1024 + lane * 16;           // phys bytes within 8KB issue
    const int fwl   = wl ^ (((wl >> 7) & 7) << 4);
    const int rbase = fwl >> 7;                          // 0..63
    const int cbase = (fwl & 127) >> 1;                  // {0,8,...,56}

    const bf16* pA = A + (size_t)(m0 + rbase) * K + cbase;
    const bf16* pB = B + (size_t)(n0 + rbase) * K + cbase;

    char* const sA0 = smem;
    char* const sB0 = smem + 32768;
    char* const sA1 = smem + 65536;
    char* const sB1 = smem + 98304;
    const int wslot = wave * 1024;

    // ---- prologue: stage K-tiles 0 (buf0) and 1 (buf1) ----
#pragma unroll
    for (int h = 0; h < 2; ++h)
#pragma unroll
        for (int i = 0; i < 2; ++i) {
            const size_t go = (size_t)(h * 128 + i * 64) * K;
            const int    lo = h * 16384 + i * 8192 + wslot;
            async_load16(pA + go, sA0 + lo);
            async_load16(pB + go, sB0 + lo);
        }
#pragma unroll
    for (int h = 0; h < 2; ++h)
#pragma unroll
        for (int i = 0; i < 2; ++i) {
            const size_t go = (size_t)(h * 128 + i * 64) * K;
            const int    lo = h * 16384 + i * 8192 + wslot;
            async_load16(pA + GBK + go, sA1 + lo);
            async_load16(pB + GBK + go, sB1 + lo);
        }
    asm volatile("s_waitcnt vmcnt(8)" ::: "memory");  // tile 0 landed, tile 1 in flight
    bar_nodrain();

    // --- read-side addressing: swizzle bit pattern is constant per thread ---
    const int sw   = (r16 & 7) << 4;
    const int c0   = (quad * 16) ^ sw;          // ks=0 column bytes
    const int c1   = (64 + quad * 16) ^ sw;     // ks=1
    const int rowA = (wr * 128 + r16) * 128;    // frag row base, bytes
    const int rowB = (wc * 64 + r16) * 128;

    f32x4 acc[8][4];
#pragma unroll
    for (int i = 0; i < 8; ++i)
#pragma unroll
        for (int j = 0; j < 4; ++j) acc[i][j] = (f32x4){0.f, 0.f, 0.f, 0.f};

    const bf16* qA = pA + 2 * GBK;   // k-offset of tile kt+2
    const bf16* qB = pB + 2 * GBK;

    for (int kt = 0; kt < GNT; ++kt) {
        char* const sA = (kt & 1) ? sA1 : sA0;
        char* const sB = (kt & 1) ? sB1 : sB0;
        const char* rA = sA + rowA;
        const char* rB = sB + rowB;

        bf16x8 a[4][2], b[4][2];
        // P0: ds_read A rows [wr*128, +64) + all 4 B frag columns (16 reads)
#pragma unroll
        for (int i = 0; i < 4; ++i) {
            a[i][0] = *(const bf16x8*)(rA + i * 2048 + c0);
            a[i][1] = *(const bf16x8*)(rA + i * 2048 + c1);
        }
#pragma unroll
        for (int j = 0; j < 4; ++j) {
            b[j][0] = *(const bf16x8*)(rB + j * 2048 + c0);
            b[j][1] = *(const bf16x8*)(rB + j * 2048 + c1);
        }
        CLUSTER(0, 0);
        // P1: pure MFMA on held regs
        CLUSTER(0, 2);
        // P2: reload A frags with rows [wr*128+64, +64) (8 reads)
#pragma unroll
        for (int i = 0; i < 4; ++i) {
            a[i][0] = *(const bf16x8*)(rA + (i + 4) * 2048 + c0);
            a[i][1] = *(const bf16x8*)(rA + (i + 4) * 2048 + c1);
        }
        CLUSTER(4, 0);
        bar_nodrain();   // all waves done reading this buffer for tile kt
        // P3: stage tile kt+2 into the buffer we just finished reading
        if (kt < GNT - 2) {
#pragma unroll
            for (int h = 0; h < 2; ++h)
#pragma unroll
                for (int i = 0; i < 2; ++i) {
                    const size_t go = (size_t)(h * 128 + i * 64) * K;
                    const int    lo = h * 16384 + i * 8192 + wslot;
                    async_load16(qA + go, sA + lo);
                    async_load16(qB + go, sB + lo);
                }
            qA += GBK; qB += GBK;
        }
        CLUSTER(4, 2);
        if (kt < GNT - 2) {
            // tile kt+1 (8 oldest) must have landed; tile kt+2 (8 newest) stays in flight
            asm volatile("s_waitcnt vmcnt(8)" ::: "memory");
            bar_nodrain();
        } else if (kt == GNT - 2) {
            asm volatile("s_waitcnt vmcnt(0)" ::: "memory");  // epilogue drain
            bar_nodrain();
        }
    }

    // ---- epilogue: C/D layout col=lane&15, row=quad*4+reg ----
    float bj[4];
#pragma unroll
    for (int j = 0; j < 4; ++j) bj[j] = bias[n0 + wc * 64 + j * 16 + r16];
#pragma unroll
    for (int i = 0; i < 8; ++i) {
#pragma unroll
        for (int r = 0; r < 4; ++r) {
            const int m = m0 + wr * 128 + i * 16 + quad * 4 + r;
            float* crow = C + (size_t)m * N + n0 + wc * 64 + r16;
#pragma unroll
            for (int j = 0; j < 4; ++j) crow[j * 16] = acc[i][j][r] + bj[j];
        }
    }
}

// ---------- m97-style 128^2 GEMM kept as launch-mechanics fallback ----------
#define BM 128
#define BN 128
#define BK 32

__global__ __launch_bounds__(256) void gemm_bt(const bf16* __restrict__ A,   // [M][K]
                                               const bf16* __restrict__ B,   // [N][K]
                                               const float* __restrict__ bias,
                                               float* __restrict__ C) {     // [M][N]
    constexpr int M = TOKENS, N = OUT_F, K = IN_F;
    (void)M;
    __shared__ bf16 As[BM * BK];
    __shared__ bf16 Bs[BN * BK];

    const int t = threadIdx.x;
    const int wave = t >> 6, lane = t & 63;
    const int quad = lane >> 4, r16 = lane & 15;
    const int wr = wave >> 1, wc = wave & 1;
    const int m0 = blockIdx.y * BM;
    const int n0 = blockIdx.x * BN;

    f32x4 acc[4][4];
#pragma unroll
    for (int i = 0; i < 4; i++)
#pragma unroll
        for (int j = 0; j < 4; j++) acc[i][j] = (f32x4){0.f, 0.f, 0.f, 0.f};

    const int c0r = t >> 2, c0c = (t & 3) * 8;
    const int c1r = (256 + t) >> 2, c1c = ((256 + t) & 3) * 8;
    bf16* lA0 = As + (size_t)(wave * 64) * 8;
    bf16* lA1 = As + (size_t)(256 + wave * 64) * 8;
    bf16* lB0 = Bs + (size_t)(wave * 64) * 8;
    bf16* lB1 = Bs + (size_t)(256 + wave * 64) * 8;
    const bf16* gA = A + (size_t)m0 * K;
    const bf16* gB = B + (size_t)n0 * K;

    for (int k0 = 0; k0 < K; k0 += BK) {
        async_load16(gA + (size_t)c0r * K + k0 + c0c, lA0);
        async_load16(gA + (size_t)c1r * K + k0 + c1c, lA1);
        async_load16(gB + (size_t)c0r * K + k0 + c0c, lB0);
        async_load16(gB + (size_t)c1r * K + k0 + c1c, lB1);
        __syncthreads();

        bf16x8 af[4], bfr[4];
#pragma unroll
        for (int i = 0; i < 4; i++)
            af[i] = *(const bf16x8*)(As + (wr * 64 + i * 16 + r16) * BK + quad * 8);
#pragma unroll
        for (int j = 0; j < 4; j++)
            bfr[j] = *(const bf16x8*)(Bs + (wc * 64 + j * 16 + r16) * BK + quad * 8);

#pragma unroll
        for (int i = 0; i < 4; i++)
#pragma unroll
            for (int j = 0; j < 4; j++)
                acc[i][j] = __builtin_amdgcn_mfma_f32_16x16x32_bf16(af[i], bfr[j], acc[i][j], 0, 0, 0);
        __syncthreads();
    }

    float bj[4];
#pragma unroll
    for (int j = 0; j < 4; j++) bj[j] = bias[n0 + wc * 64 + j * 16 + r16];
#pragma unroll
    for (int i = 0; i < 4; i++) {
#pragma unroll
        for (int r = 0; r < 4; r++) {
            int m = m0 + wr * 64 + i * 16 + quad * 4 + r;
            float* crow = C + (size_t)m * N + n0 + wc * 64 + r16;
#pragma unroll
            for (int j = 0; j < 4; j++) crow[j * 16] = acc[i][j][r] + bj[j];
        }
    }
}

// ---------- correctness fallback if workspace too small ----------
#define FT 16
__global__ void gemm_fallback(const float* __restrict__ x, const int* __restrict__ codes,
                              const float* __restrict__ absmax, const float* __restrict__ bias,
                              float* __restrict__ C) {
    __shared__ float xs[FT][FT];
    __shared__ float ws_[FT][FT + 1];
    int tx = threadIdx.x, ty = threadIdx.y;
    int n = blockIdx.x * FT + tx;
    int m = blockIdx.y * FT + ty;
    float acc = 0.f;
    for (int k0 = 0; k0 < IN_F; k0 += FT) {
        xs[ty][tx] = x[(size_t)m * IN_F + k0 + tx];
        int o = blockIdx.x * FT + ty;
        size_t widx = (size_t)o * IN_F + k0 + tx;
        ws_[ty][tx] = NF4[codes[widx]] * absmax[widx >> 6];
        __syncthreads();
#pragma unroll
        for (int k = 0; k < FT; k++) acc += xs[ty][k] * ws_[tx][k];
        __syncthreads();
    }
    C[(size_t)m * OUT_F + n] = acc + bias[n];
}

extern "C" void kernel_launch(void* const* d_in, const int* in_sizes, int n_in,
                              void* d_out, int out_size, void* d_ws, size_t ws_size,
                              hipStream_t stream) {
    const float* x      = (const float*)d_in[0];
    const int*   codes  = (const int*)d_in[1];
    const float* absmax = (const float*)d_in[2];
    const float* bias   = (const float*)d_in[3];
    float* out = (float*)d_out;

    const size_t xb_elems = (size_t)TOKENS * IN_F;
    const size_t w_elems  = (size_t)OUT_F * IN_F;
    const size_t need = (xb_elems + w_elems) * sizeof(bf16);

    if (ws_size >= need) {
        bf16* xb = (bf16*)d_ws;
        bf16* W  = xb + xb_elems;
        cvt_kernel<<<(int)(xb_elems / 8 / 256), 256, 0, stream>>>(x, xb);
        dequant_kernel<<<(int)(w_elems / 8 / 256), 256, 0, stream>>>(codes, absmax, W);

        static int smem_ok = -1;
        if (smem_ok < 0) {
            hipError_t e = hipFuncSetAttribute(
                reinterpret_cast<const void*>(gemm256),
                hipFuncAttributeMaxDynamicSharedMemorySize, 131072);
            smem_ok = (e == hipSuccess) ? 1 : 0;
        }
        bool launched = false;
        if (smem_ok) {
            (void)hipGetLastError();  // clear sticky error
            gemm256<<<dim3(2048), 512, 131072, stream>>>(xb, W, bias, out);
            launched = (hipGetLastError() == hipSuccess);
        }
        if (!launched) {
            gemm_bt<<<dim3(OUT_F / BN, TOKENS / BM), 256, 0, stream>>>(xb, W, bias, out);
        }
    } else {
        gemm_fallback<<<dim3(OUT_F / FT, TOKENS / FT), dim3(FT, FT), 0, stream>>>(
            x, codes, absmax, bias, out);
    }
}

// Round 2
// 1615.412 us; speedup vs baseline: 1.1929x; 1.0610x over previous
//
#include <hip/hip_runtime.h>
#include <hip/hip_bf16.h>
#include <stdint.h>

// Problem constants (fixed by the reference)
#define TOKENS 8192
#define IN_F   4096
#define OUT_F  16384

typedef __bf16 bf16;
typedef __bf16 bf16x8 __attribute__((ext_vector_type(8)));
typedef float  f32x4  __attribute__((ext_vector_type(4)));

__device__ __constant__ float NF4[16] = {
    -1.0f, -0.6961928009986877f, -0.5250730514526367f, -0.39491748809814453f,
    -0.28444138169288635f, -0.18477343022823334f, -0.09105003625154495f, 0.0f,
    0.07958029955625534f, 0.16093020141124725f, 0.24611230194568634f,
    0.33791524171829224f, 0.44070982933044434f, 0.5626170039176941f,
    0.7229568362236023f, 1.0f};

// ---------- x fp32 -> bf16 ----------
__global__ __launch_bounds__(256) void cvt_kernel(const float* __restrict__ x,
                                                  bf16* __restrict__ xb) {
    size_t base = ((size_t)blockIdx.x * blockDim.x + threadIdx.x) * 8;
    float4 a = *(const float4*)(x + base);
    float4 b = *(const float4*)(x + base + 4);
    bf16x8 w;
    w[0] = (bf16)a.x; w[1] = (bf16)a.y; w[2] = (bf16)a.z; w[3] = (bf16)a.w;
    w[4] = (bf16)b.x; w[5] = (bf16)b.y; w[6] = (bf16)b.z; w[7] = (bf16)b.w;
    *(bf16x8*)(xb + base) = w;
}

// ---------- NF4 dequant: codes(int32)+absmax -> W bf16 [OUT_F][IN_F] ----------
__global__ __launch_bounds__(256) void dequant_kernel(const int* __restrict__ codes,
                                                      const float* __restrict__ absmax,
                                                      bf16* __restrict__ W) {
    __shared__ float lut[16];
    if (threadIdx.x < 16) lut[threadIdx.x] = NF4[threadIdx.x];
    __syncthreads();
    size_t base = ((size_t)blockIdx.x * blockDim.x + threadIdx.x) * 8;
    float scale = absmax[base >> 6];   // 8 consecutive elems share one 64-block
    int4 c0 = *(const int4*)(codes + base);
    int4 c1 = *(const int4*)(codes + base + 4);
    bf16x8 w;
    w[0] = (bf16)(lut[c0.x] * scale);
    w[1] = (bf16)(lut[c0.y] * scale);
    w[2] = (bf16)(lut[c0.z] * scale);
    w[3] = (bf16)(lut[c0.w] * scale);
    w[4] = (bf16)(lut[c1.x] * scale);
    w[5] = (bf16)(lut[c1.y] * scale);
    w[6] = (bf16)(lut[c1.z] * scale);
    w[7] = (bf16)(lut[c1.w] * scale);
    *(bf16x8*)(W + base) = w;
}

typedef const unsigned int __attribute__((address_space(1)))* gas_ptr;
typedef unsigned int __attribute__((address_space(3)))* las_ptr;

__device__ __forceinline__ void async_load16(const void* g, void* l) {
    __builtin_amdgcn_global_load_lds((gas_ptr)(uintptr_t)g, (las_ptr)(uintptr_t)l, 16, 0, 0);
}

// ======================================================================
// 256x256 tile, BK=64, 8 waves (2M x 4N), double-buffered 128KB LDS.
// R2: full m201-style 8-phase fine interleave. Per K-tile, 4 phases:
//   φ1: 12 ds_read (a0-3,b0-1)                 | 16 MFMA quad(m0-3,n0-1)
//   φ2:  4 ds_read (b2-3) + stage A(h,0) t+2   | 16 MFMA quad(m0-3,n2-3)
//   φ3:  8 ds_read (a4-7) + stage B(all) t+2   | 16 MFMA quad(m4-7,n0-1)
//   φ4:  stage A(h,1) t+2 + vmcnt(8)           | 16 MFMA quad(m4-7,n2-3)
// Each phase: reads/stages; sched_barrier; s_barrier; lgkmcnt(0);
// sched_barrier; setprio(1); MFMA; setprio(0); barrier.
// Hazards: A(h,0) rows fully read+drained at φ1, B by φ2, A(h,1) by φ3 —
// every stage lands strictly after the drain of the region it overwrites.
// vmcnt(8) at φ4 = tile t+2's 8 loads in flight, tile t+1 landed.
// ======================================================================
#define GBM 256
#define GBN 256
#define GBK 64
#define GNT (IN_F / GBK)   // 64 K-tiles

__device__ __forceinline__ void bar_nodrain() {
    __builtin_amdgcn_sched_barrier(0);
    __builtin_amdgcn_s_barrier();
    __builtin_amdgcn_sched_barrier(0);
}

__device__ __forceinline__ void phase_pre() {   // entry barrier + own-read drain
    __builtin_amdgcn_sched_barrier(0);
    __builtin_amdgcn_s_barrier();
    asm volatile("s_waitcnt lgkmcnt(0)" ::: "memory");
    __builtin_amdgcn_sched_barrier(0);
}

#define MFMA16(I0, J0)                                                               \
    do {                                                                             \
        __builtin_amdgcn_s_setprio(1);                                               \
        _Pragma("unroll") for (int i_ = 0; i_ < 4; ++i_) {                           \
            _Pragma("unroll") for (int j_ = 0; j_ < 2; ++j_) {                       \
                acc[(I0) + i_][(J0) + j_] = __builtin_amdgcn_mfma_f32_16x16x32_bf16( \
                    a[i_][0], b[(J0) + j_][0], acc[(I0) + i_][(J0) + j_], 0, 0, 0);  \
                acc[(I0) + i_][(J0) + j_] = __builtin_amdgcn_mfma_f32_16x16x32_bf16( \
                    a[i_][1], b[(J0) + j_][1], acc[(I0) + i_][(J0) + j_], 0, 0, 0);  \
            }                                                                        \
        }                                                                            \
        __builtin_amdgcn_s_setprio(0);                                               \
    } while (0)

__global__ __launch_bounds__(512, 2) void gemm256(const bf16* __restrict__ A,   // [M][K]
                                                  const bf16* __restrict__ B,   // [N][K]
                                                  const float* __restrict__ bias,
                                                  float* __restrict__ C) {      // [M][N]
    constexpr int K = IN_F, N = OUT_F;
    extern __shared__ char smem[];  // 131072: buf0{A 32K, B 32K} buf1{A 32K, B 32K}

    const int t    = threadIdx.x;
    const int wave = t >> 6, lane = t & 63;
    const int quad = lane >> 4, r16 = lane & 15;
    const int wr = wave >> 2, wc = wave & 3;   // 2 (M) x 4 (N) waves

    // XCD-aware bijective swizzle: 2048 blocks, 8 XCDs, 256 per chunk
    const int g  = blockIdx.x;
    const int s  = (g & 7) * (2048 / 8) + (g >> 3);
    const int by = s >> 6;          // 32 M-tiles
    const int bx = s & 63;          // 64 N-tiles
    const int m0 = by * GBM;
    const int n0 = bx * GBN;

    // --- staging source mapping (involution: logical f = phys w ^ ((w>>7&7)<<4)) ---
    // global_load_lds writes linearly (wave base + lane*16); pre-swizzle the SOURCE.
    const int wl    = wave * 1024 + lane * 16;           // phys bytes within 8KB issue
    const int fwl   = wl ^ (((wl >> 7) & 7) << 4);
    const int rbase = fwl >> 7;                          // 0..63
    const int cbase = (fwl & 127) >> 1;                  // {0,8,...,56}

    const bf16* pA = A + (size_t)(m0 + rbase) * K + cbase;
    const bf16* pB = B + (size_t)(n0 + rbase) * K + cbase;

    char* const sA0 = smem;
    char* const sB0 = smem + 32768;
    char* const sA1 = smem + 65536;
    char* const sB1 = smem + 98304;
    const int wslot = wave * 1024;

    // ---- prologue: stage K-tiles 0 (buf0) and 1 (buf1) ----
#pragma unroll
    for (int h = 0; h < 2; ++h)
#pragma unroll
        for (int i = 0; i < 2; ++i) {
            const size_t go = (size_t)(h * 128 + i * 64) * K;
            const int    lo = h * 16384 + i * 8192 + wslot;
            async_load16(pA + go, sA0 + lo);
            async_load16(pB + go, sB0 + lo);
        }
#pragma unroll
    for (int h = 0; h < 2; ++h)
#pragma unroll
        for (int i = 0; i < 2; ++i) {
            const size_t go = (size_t)(h * 128 + i * 64) * K;
            const int    lo = h * 16384 + i * 8192 + wslot;
            async_load16(pA + GBK + go, sA1 + lo);
            async_load16(pB + GBK + go, sB1 + lo);
        }
    asm volatile("s_waitcnt vmcnt(8)" ::: "memory");  // tile 0 landed, tile 1 in flight
    bar_nodrain();

    // --- read-side addressing: swizzle bit pattern is constant per thread ---
    const int sw   = (r16 & 7) << 4;
    const int c0   = (quad * 16) ^ sw;          // ks=0 column bytes
    const int c1   = (64 + quad * 16) ^ sw;     // ks=1
    const int rowA = (wr * 128 + r16) * 128;    // frag row base, bytes
    const int rowB = (wc * 64 + r16) * 128;

    f32x4 acc[8][4];
#pragma unroll
    for (int i = 0; i < 8; ++i)
#pragma unroll
        for (int j = 0; j < 4; ++j) acc[i][j] = (f32x4){0.f, 0.f, 0.f, 0.f};

    const bf16* qA = pA + 2 * GBK;   // k-offset of tile kt+2
    const bf16* qB = pB + 2 * GBK;

#pragma unroll 2
    for (int kt = 0; kt < GNT; ++kt) {
        char* const sA = (kt & 1) ? sA1 : sA0;
        char* const sB = (kt & 1) ? sB1 : sB0;
        const char* rA = sA + rowA;
        const char* rB = sB + rowB;
        const bool do_stage = (kt < GNT - 2);

        bf16x8 a[4][2], b[4][2];

        // ---- φ1: 12 ds_read (a0-3, b0-1) ----
#pragma unroll
        for (int i = 0; i < 4; ++i) {
            a[i][0] = *(const bf16x8*)(rA + i * 2048 + c0);
            a[i][1] = *(const bf16x8*)(rA + i * 2048 + c1);
        }
#pragma unroll
        for (int j = 0; j < 2; ++j) {
            b[j][0] = *(const bf16x8*)(rB + j * 2048 + c0);
            b[j][1] = *(const bf16x8*)(rB + j * 2048 + c1);
        }
        asm volatile("s_waitcnt lgkmcnt(8)" ::: "memory");  // start draining pre-barrier
        phase_pre();
        MFMA16(0, 0);
        bar_nodrain();

        // ---- φ2: 4 ds_read (b2-3) + stage A(h,0) of t+2 ----
#pragma unroll
        for (int j = 2; j < 4; ++j) {
            b[j][0] = *(const bf16x8*)(rB + j * 2048 + c0);
            b[j][1] = *(const bf16x8*)(rB + j * 2048 + c1);
        }
        if (do_stage) {
            async_load16(qA, sA + wslot);                                  // rows 0-63
            async_load16(qA + (size_t)128 * K, sA + 16384 + wslot);        // rows 128-191
        }
        phase_pre();
        MFMA16(0, 2);
        bar_nodrain();

        // ---- φ3: 8 ds_read (a4-7) + stage B(all) of t+2 ----
#pragma unroll
        for (int i = 0; i < 4; ++i) {
            a[i][0] = *(const bf16x8*)(rA + (i + 4) * 2048 + c0);
            a[i][1] = *(const bf16x8*)(rA + (i + 4) * 2048 + c1);
        }
        if (do_stage) {
            async_load16(qB, sB + wslot);                                  // rows 0-63
            async_load16(qB + (size_t)64 * K, sB + 8192 + wslot);          // rows 64-127
            async_load16(qB + (size_t)128 * K, sB + 16384 + wslot);        // rows 128-191
            async_load16(qB + (size_t)192 * K, sB + 24576 + wslot);        // rows 192-255
        }
        phase_pre();
        MFMA16(4, 0);
        bar_nodrain();

        // ---- φ4: stage A(h,1) of t+2, counted vmcnt ----
        if (do_stage) {
            async_load16(qA + (size_t)64 * K, sA + 8192 + wslot);          // rows 64-127
            async_load16(qA + (size_t)192 * K, sA + 24576 + wslot);        // rows 192-255
            qA += GBK; qB += GBK;
            asm volatile("s_waitcnt vmcnt(8)" ::: "memory");  // t+1 landed, t+2 in flight
        } else if (kt == GNT - 2) {
            asm volatile("s_waitcnt vmcnt(0)" ::: "memory");  // epilogue drain
        }
        __builtin_amdgcn_sched_barrier(0);
        __builtin_amdgcn_s_barrier();
        __builtin_amdgcn_sched_barrier(0);
        MFMA16(4, 2);
        bar_nodrain();
    }

    // ---- epilogue: C/D layout col=lane&15, row=quad*4+reg ----
    float bj[4];
#pragma unroll
    for (int j = 0; j < 4; ++j) bj[j] = bias[n0 + wc * 64 + j * 16 + r16];
#pragma unroll
    for (int i = 0; i < 8; ++i) {
#pragma unroll
        for (int r = 0; r < 4; ++r) {
            const int m = m0 + wr * 128 + i * 16 + quad * 4 + r;
            float* crow = C + (size_t)m * N + n0 + wc * 64 + r16;
#pragma unroll
            for (int j = 0; j < 4; ++j) crow[j * 16] = acc[i][j][r] + bj[j];
        }
    }
}

// ---------- m97-style 128^2 GEMM kept as launch-mechanics fallback ----------
#define BM 128
#define BN 128
#define BK 32

__global__ __launch_bounds__(256) void gemm_bt(const bf16* __restrict__ A,   // [M][K]
                                               const bf16* __restrict__ B,   // [N][K]
                                               const float* __restrict__ bias,
                                               float* __restrict__ C) {     // [M][N]
    constexpr int M = TOKENS, N = OUT_F, K = IN_F;
    (void)M;
    __shared__ bf16 As[BM * BK];
    __shared__ bf16 Bs[BN * BK];

    const int t = threadIdx.x;
    const int wave = t >> 6, lane = t & 63;
    const int quad = lane >> 4, r16 = lane & 15;
    const int wr = wave >> 1, wc = wave & 1;
    const int m0 = blockIdx.y * BM;
    const int n0 = blockIdx.x * BN;

    f32x4 acc[4][4];
#pragma unroll
    for (int i = 0; i < 4; i++)
#pragma unroll
        for (int j = 0; j < 4; j++) acc[i][j] = (f32x4){0.f, 0.f, 0.f, 0.f};

    const int c0r = t >> 2, c0c = (t & 3) * 8;
    const int c1r = (256 + t) >> 2, c1c = ((256 + t) & 3) * 8;
    bf16* lA0 = As + (size_t)(wave * 64) * 8;
    bf16* lA1 = As + (size_t)(256 + wave * 64) * 8;
    bf16* lB0 = Bs + (size_t)(wave * 64) * 8;
    bf16* lB1 = Bs + (size_t)(256 + wave * 64) * 8;
    const bf16* gA = A + (size_t)m0 * K;
    const bf16* gB = B + (size_t)n0 * K;

    for (int k0 = 0; k0 < K; k0 += BK) {
        async_load16(gA + (size_t)c0r * K + k0 + c0c, lA0);
        async_load16(gA + (size_t)c1r * K + k0 + c1c, lA1);
        async_load16(gB + (size_t)c0r * K + k0 + c0c, lB0);
        async_load16(gB + (size_t)c1r * K + k0 + c1c, lB1);
        __syncthreads();

        bf16x8 af[4], bfr[4];
#pragma unroll
        for (int i = 0; i < 4; i++)
            af[i] = *(const bf16x8*)(As + (wr * 64 + i * 16 + r16) * BK + quad * 8);
#pragma unroll
        for (int j = 0; j < 4; j++)
            bfr[j] = *(const bf16x8*)(Bs + (wc * 64 + j * 16 + r16) * BK + quad * 8);

#pragma unroll
        for (int i = 0; i < 4; i++)
#pragma unroll
            for (int j = 0; j < 4; j++)
                acc[i][j] = __builtin_amdgcn_mfma_f32_16x16x32_bf16(af[i], bfr[j], acc[i][j], 0, 0, 0);
        __syncthreads();
    }

    float bj[4];
#pragma unroll
    for (int j = 0; j < 4; j++) bj[j] = bias[n0 + wc * 64 + j * 16 + r16];
#pragma unroll
    for (int i = 0; i < 4; i++) {
#pragma unroll
        for (int r = 0; r < 4; r++) {
            int m = m0 + wr * 64 + i * 16 + quad * 4 + r;
            float* crow = C + (size_t)m * N + n0 + wc * 64 + r16;
#pragma unroll
            for (int j = 0; j < 4; j++) crow[j * 16] = acc[i][j][r] + bj[j];
        }
    }
}

// ---------- correctness fallback if workspace too small ----------
#define FT 16
__global__ void gemm_fallback(const float* __restrict__ x, const int* __restrict__ codes,
                              const float* __restrict__ absmax, const float* __restrict__ bias,
                              float* __restrict__ C) {
    __shared__ float xs[FT][FT];
    __shared__ float ws_[FT][FT + 1];
    int tx = threadIdx.x, ty = threadIdx.y;
    int n = blockIdx.x * FT + tx;
    int m = blockIdx.y * FT + ty;
    float acc = 0.f;
    for (int k0 = 0; k0 < IN_F; k0 += FT) {
        xs[ty][tx] = x[(size_t)m * IN_F + k0 + tx];
        int o = blockIdx.x * FT + ty;
        size_t widx = (size_t)o * IN_F + k0 + tx;
        ws_[ty][tx] = NF4[codes[widx]] * absmax[widx >> 6];
        __syncthreads();
#pragma unroll
        for (int k = 0; k < FT; k++) acc += xs[ty][k] * ws_[tx][k];
        __syncthreads();
    }
    C[(size_t)m * OUT_F + n] = acc + bias[n];
}

extern "C" void kernel_launch(void* const* d_in, const int* in_sizes, int n_in,
                              void* d_out, int out_size, void* d_ws, size_t ws_size,
                              hipStream_t stream) {
    const float* x      = (const float*)d_in[0];
    const int*   codes  = (const int*)d_in[1];
    const float* absmax = (const float*)d_in[2];
    const float* bias   = (const float*)d_in[3];
    float* out = (float*)d_out;

    const size_t xb_elems = (size_t)TOKENS * IN_F;
    const size_t w_elems  = (size_t)OUT_F * IN_F;
    const size_t need = (xb_elems + w_elems) * sizeof(bf16);

    if (ws_size >= need) {
        bf16* xb = (bf16*)d_ws;
        bf16* W  = xb + xb_elems;
        cvt_kernel<<<(int)(xb_elems / 8 / 256), 256, 0, stream>>>(x, xb);
        dequant_kernel<<<(int)(w_elems / 8 / 256), 256, 0, stream>>>(codes, absmax, W);

        static int smem_ok = -1;
        if (smem_ok < 0) {
            hipError_t e = hipFuncSetAttribute(
                reinterpret_cast<const void*>(gemm256),
                hipFuncAttributeMaxDynamicSharedMemorySize, 131072);
            smem_ok = (e == hipSuccess) ? 1 : 0;
        }
        bool launched = false;
        if (smem_ok) {
            (void)hipGetLastError();  // clear sticky error
            gemm256<<<dim3(2048), 512, 131072, stream>>>(xb, W, bias, out);
            launched = (hipGetLastError() == hipSuccess);
        }
        if (!launched) {
            gemm_bt<<<dim3(OUT_F / BN, TOKENS / BM), 256, 0, stream>>>(xb, W, bias, out);
        }
    } else {
        gemm_fallback<<<dim3(OUT_F / FT, TOKENS / FT), dim3(FT, FT), 0, stream>>>(
            x, codes, absmax, bias, out);
    }
}